// Round 7
// baseline (156.755 us; speedup 1.0000x reference)
//
#include <hip/hip_runtime.h>
#include <math.h>

// CIoU loss, fp32, N = 4194304.
// Round 7 (= round 6 resubmit; bench never ran). TLP restructure: 1 element/
// thread, 16384 short-lived blocks -> memcpy-like wave turnover; every wave's
// 2 loads issue at wave start, waves retire fast. Single-atan identity
// retained. Deterministic two-kernel reduction.

#define EPS 1e-6f
#define NTHREADS 256

__global__ __launch_bounds__(NTHREADS) void ciou_partial_kernel(
    const float4* __restrict__ pred,
    const float4* __restrict__ tgt,
    float* __restrict__ partials,
    int n)
{
    const float inv_pi2_4 = 4.0f / (float)(M_PI * M_PI);
    int i = blockIdx.x * NTHREADS + threadIdx.x;

    float acc = 0.0f;
    if (i < n) {
        float4 p = pred[i];
        float4 t = tgt[i];

        float pw = p.z - p.x, ph = p.w - p.y;
        float tw = t.z - t.x, th = t.w - t.y;
        float area_p = pw * ph;
        float area_t = tw * th;

        float ix = fminf(p.z, t.z) - fmaxf(p.x, t.x);
        float iy = fminf(p.w, t.w) - fmaxf(p.y, t.y);
        ix = fmaxf(ix, 0.0f);
        iy = fmaxf(iy, 0.0f);
        float inter = ix * iy;
        float uni = area_p + area_t - inter;
        float iou = inter / fmaxf(uni, EPS);

        float dcx = 0.5f * ((p.x + p.z) - (t.x + t.z));
        float dcy = 0.5f * ((p.y + p.w) - (t.y + t.w));
        float center_d = dcx * dcx + dcy * dcy;

        float ex = fmaxf(p.z, t.z) - fminf(p.x, t.x);
        float ey = fmaxf(p.w, t.w) - fminf(p.y, t.y);
        float diag_d = ex * ex + ey * ey;

        // atan(tw/th) - atan(pw/ph) == atan((tw*ph - pw*th)/(th*ph + tw*pw));
        // both ratios > 0 so the denominator is > 0.
        float num = tw * ph - pw * th;
        float den = th * ph + tw * pw;
        float da = atanf(num / den);
        float v = inv_pi2_4 * da * da;
        float alpha = v / (1.0f - iou + v + EPS);

        float ciou = iou - center_d / fmaxf(diag_d, EPS) + alpha * v;
        acc = 1.0f - ciou;
    }

    // wave-64 reduce
    #pragma unroll
    for (int off = 32; off > 0; off >>= 1)
        acc += __shfl_down(acc, off, 64);

    __shared__ float wsum[NTHREADS / 64];
    int lane = threadIdx.x & 63;
    int wid  = threadIdx.x >> 6;
    if (lane == 0) wsum[wid] = acc;
    __syncthreads();
    if (threadIdx.x == 0) {
        float b = wsum[0];
        #pragma unroll
        for (int w = 1; w < NTHREADS / 64; ++w) b += wsum[w];
        partials[blockIdx.x] = b;
    }
}

__global__ __launch_bounds__(NTHREADS) void ciou_finalize_kernel(
    const float* __restrict__ partials, float* __restrict__ out, int nblocks, float inv_n)
{
    double acc = 0.0;
    for (int i = threadIdx.x; i < nblocks; i += NTHREADS)
        acc += (double)partials[i];

    #pragma unroll
    for (int off = 32; off > 0; off >>= 1)
        acc += __shfl_down(acc, off, 64);

    __shared__ double wsum[NTHREADS / 64];
    int lane = threadIdx.x & 63;
    int wid  = threadIdx.x >> 6;
    if (lane == 0) wsum[wid] = acc;
    __syncthreads();
    if (threadIdx.x == 0) {
        double b = wsum[0];
        #pragma unroll
        for (int w = 1; w < NTHREADS / 64; ++w) b += wsum[w];
        out[0] = (float)(b * (double)inv_n);
    }
}

extern "C" void kernel_launch(void* const* d_in, const int* in_sizes, int n_in,
                              void* d_out, int out_size, void* d_ws, size_t ws_size,
                              hipStream_t stream)
{
    const float4* pred = (const float4*)d_in[0];
    const float4* tgt  = (const float4*)d_in[1];
    int n = in_sizes[0] / 4;
    int nblocks = (n + NTHREADS - 1) / NTHREADS;   // 16384 for N=4194304 (64KB of d_ws)

    float* partials = (float*)d_ws;
    float* out = (float*)d_out;

    ciou_partial_kernel<<<nblocks, NTHREADS, 0, stream>>>(pred, tgt, partials, n);
    ciou_finalize_kernel<<<1, NTHREADS, 0, stream>>>(partials, out, nblocks, 1.0f / (float)n);
}

// Round 14
// 152.826 us; speedup vs baseline: 1.0257x; 1.0257x over previous
//
#include <hip/hip_runtime.h>
#include <math.h>

// CIoU loss, fp32, N = 4194304.
// Round 14 (= round 11/12/13 resubmit; bench never ran). Forced MLP via
// inline asm: 8 volatile global_load_dwordx4 issued up-front (volatile asm
// keeps program order), staged s_waitcnt vmcnt(6/4/2/0) + sched_barrier(0)
// fences (rule-18 pattern; tied "+v" float4 operands don't compile).
// 4 elems/thread, 4096 blocks. Deterministic two-kernel reduction unchanged.

#define EPS 1e-6f
#define NTHREADS 256
#define PER_THREAD 4

__device__ __forceinline__ float ciou_loss(float4 p, float4 t)
{
    const float inv_pi2_4 = 4.0f / (float)(M_PI * M_PI);

    float pw = p.z - p.x, ph = p.w - p.y;
    float tw = t.z - t.x, th = t.w - t.y;
    float area_p = pw * ph;
    float area_t = tw * th;

    float ix = fminf(p.z, t.z) - fmaxf(p.x, t.x);
    float iy = fminf(p.w, t.w) - fmaxf(p.y, t.y);
    ix = fmaxf(ix, 0.0f);
    iy = fmaxf(iy, 0.0f);
    float inter = ix * iy;
    float uni = area_p + area_t - inter;
    float iou = inter / fmaxf(uni, EPS);

    float dcx = 0.5f * ((p.x + p.z) - (t.x + t.z));
    float dcy = 0.5f * ((p.y + p.w) - (t.y + t.w));
    float center_d = dcx * dcx + dcy * dcy;

    float ex = fmaxf(p.z, t.z) - fminf(p.x, t.x);
    float ey = fmaxf(p.w, t.w) - fminf(p.y, t.y);
    float diag_d = ex * ex + ey * ey;

    // atan(tw/th) - atan(pw/ph) == atan((tw*ph - pw*th)/(th*ph + tw*pw));
    // both ratios > 0 so the denominator is > 0.
    float num = tw * ph - pw * th;
    float den = th * ph + tw * pw;
    float da = atanf(num / den);
    float v = inv_pi2_4 * da * da;
    float alpha = v / (1.0f - iou + v + EPS);

    float ciou = iou - center_d / fmaxf(diag_d, EPS) + alpha * v;
    return 1.0f - ciou;
}

#define ASM_LOAD(dst, addr) \
    asm volatile("global_load_dwordx4 %0, %1, off" : "=&v"(dst) : "v"(addr) : "memory")

// Wait until at most N vector-memory ops outstanding, then fence the
// scheduler so no compute hoists above the wait (guide rule 18).
#define WAITCNT_FENCE(N)                                        \
    do {                                                        \
        asm volatile("s_waitcnt vmcnt(" #N ")" ::: "memory");   \
        __builtin_amdgcn_sched_barrier(0);                      \
    } while (0)

__global__ __launch_bounds__(NTHREADS) void ciou_partial_kernel(
    const float4* __restrict__ pred,
    const float4* __restrict__ tgt,
    float* __restrict__ partials,
    int n)
{
    float acc;
    const int tid = blockIdx.x * NTHREADS + threadIdx.x;
    const int stride = gridDim.x * NTHREADS;

    if (n == stride * PER_THREAD) {
        float4 p0, p1, p2, p3, t0, t1, t2, t3;
        // Issue all 8 loads up-front; volatile asm preserves program order,
        // so 8 dwordx4 (8KB/wave) are in flight before any wait.
        ASM_LOAD(p0, pred + tid + 0 * stride);
        ASM_LOAD(t0, tgt  + tid + 0 * stride);
        ASM_LOAD(p1, pred + tid + 1 * stride);
        ASM_LOAD(t1, tgt  + tid + 1 * stride);
        ASM_LOAD(p2, pred + tid + 2 * stride);
        ASM_LOAD(t2, tgt  + tid + 2 * stride);
        ASM_LOAD(p3, pred + tid + 3 * stride);
        ASM_LOAD(t3, tgt  + tid + 3 * stride);

        float acc0 = 0.0f, acc1 = 0.0f;
        // Staged waits: compute elem k while 6-2k loads remain in flight.
        WAITCNT_FENCE(6);
        acc0 += ciou_loss(p0, t0);
        WAITCNT_FENCE(4);
        acc1 += ciou_loss(p1, t1);
        WAITCNT_FENCE(2);
        acc0 += ciou_loss(p2, t2);
        WAITCNT_FENCE(0);
        acc1 += ciou_loss(p3, t3);
        acc = acc0 + acc1;
    } else {
        acc = 0.0f;
        for (int i = tid; i < n; i += stride)
            acc += ciou_loss(pred[i], tgt[i]);
    }

    // wave-64 reduce
    #pragma unroll
    for (int off = 32; off > 0; off >>= 1)
        acc += __shfl_down(acc, off, 64);

    __shared__ float wsum[NTHREADS / 64];
    int lane = threadIdx.x & 63;
    int wid  = threadIdx.x >> 6;
    if (lane == 0) wsum[wid] = acc;
    __syncthreads();
    if (threadIdx.x == 0) {
        float b = wsum[0];
        #pragma unroll
        for (int w = 1; w < NTHREADS / 64; ++w) b += wsum[w];
        partials[blockIdx.x] = b;
    }
}

__global__ __launch_bounds__(NTHREADS) void ciou_finalize_kernel(
    const float* __restrict__ partials, float* __restrict__ out, int nblocks, float inv_n)
{
    double acc = 0.0;
    for (int i = threadIdx.x; i < nblocks; i += NTHREADS)
        acc += (double)partials[i];

    #pragma unroll
    for (int off = 32; off > 0; off >>= 1)
        acc += __shfl_down(acc, off, 64);

    __shared__ double wsum[NTHREADS / 64];
    int lane = threadIdx.x & 63;
    int wid  = threadIdx.x >> 6;
    if (lane == 0) wsum[wid] = acc;
    __syncthreads();
    if (threadIdx.x == 0) {
        double b = wsum[0];
        #pragma unroll
        for (int w = 1; w < NTHREADS / 64; ++w) b += wsum[w];
        out[0] = (float)(b * (double)inv_n);
    }
}

extern "C" void kernel_launch(void* const* d_in, const int* in_sizes, int n_in,
                              void* d_out, int out_size, void* d_ws, size_t ws_size,
                              hipStream_t stream)
{
    const float4* pred = (const float4*)d_in[0];
    const float4* tgt  = (const float4*)d_in[1];
    int n = in_sizes[0] / 4;
    int nblocks = (n + NTHREADS * PER_THREAD - 1) / (NTHREADS * PER_THREAD);  // 4096

    float* partials = (float*)d_ws;   // 4096 floats, every slot written each launch
    float* out = (float*)d_out;

    ciou_partial_kernel<<<nblocks, NTHREADS, 0, stream>>>(pred, tgt, partials, n);
    ciou_finalize_kernel<<<1, NTHREADS, 0, stream>>>(partials, out, nblocks, 1.0f / (float)n);
}